// Round 8
// baseline (458.238 us; speedup 1.0000x reference)
//
#include <hip/hip_runtime.h>
#include <hip/hip_bf16.h>

#define NNODES 20000
#define EEDGES 320000
#define FIN 1024
#define HMID 256
#define DOUT 128
#define ALPHA_BLOCKS ((NNODES + 3) / 4)

typedef __bf16 bf16x8 __attribute__((ext_vector_type(8)));
typedef __bf16 bf16x4 __attribute__((ext_vector_type(4)));
typedef __bf16 bf16x2 __attribute__((ext_vector_type(2)));
typedef float f32x4 __attribute__((ext_vector_type(4)));

typedef const __attribute__((address_space(1))) void* gas_ptr;
typedef __attribute__((address_space(3))) void* las_ptr;
__device__ __forceinline__ void async_copy16(const void* g, void* l) {
    __builtin_amdgcn_global_load_lds((gas_ptr)g, (las_ptr)l, 16, 0, 0);
}

__device__ __forceinline__ float readlane_f(float v, int lane) {
    return __uint_as_float(__builtin_amdgcn_readlane(__float_as_uint(v), lane));
}

// ---------------- fused prep: pack_w + prep_watt + init ----------------
// blocks [0,128): Wtp packing; [128,192): Wallt/ball; [192,271): cnt/S zero.
__global__ __launch_bounds__(256) void k_prep(const float* __restrict__ Wg,
                                              const float* __restrict__ Wq, const float* __restrict__ Wk,
                                              const float* __restrict__ Wv, const float* __restrict__ Ws,
                                              const float* __restrict__ bq, const float* __restrict__ bk,
                                              const float* __restrict__ bv, const float* __restrict__ bs,
                                              __bf16* __restrict__ Wtp, __bf16* __restrict__ Wallt,
                                              float* __restrict__ ball,
                                              int* __restrict__ cnt, float* __restrict__ S) {
    int b = blockIdx.x;
    if (b < 128) {
        int tid = b * 256 + threadIdx.x;   // 32768 units
        int kk = tid >> 10;
        int rem = tid & 1023;
        int h = rem >> 9;
        int u = rem & 511;
        int kq = u >> 7, c = u & 127;
        int col = h * 128 + c;
        int k0 = kk * 32 + kq * 8;
        bf16x8 v;
#pragma unroll
        for (int j = 0; j < 8; j++)
            v[j] = (__bf16)Wg[(size_t)(k0 + j) * HMID + col];
        *(bf16x8*)(Wtp + (size_t)tid * 8) = v;
    } else if (b < 192) {
        int g = (b - 128) >> 4;
        const float* W = (g == 0) ? Wq : (g == 1) ? Wk : (g == 2) ? Wv : Ws;
        int tid = ((b - 128) & 15) * 256 + threadIdx.x;   // 4096 units
        int n = tid & 127;
        int k0u = tid >> 7;
        bf16x8 v;
#pragma unroll
        for (int j = 0; j < 8; j++)
            v[j] = (__bf16)W[(size_t)(k0u * 8 + j) * DOUT + n];
        *(bf16x8*)(Wallt + (size_t)(g * DOUT + n) * HMID + k0u * 8) = v;
        if (tid < DOUT) {
            const float* bb = (g == 0) ? bq : (g == 1) ? bk : (g == 2) ? bv : bs;
            ball[g * DOUT + tid] = bb[tid];
        }
    } else {
        int i = (b - 192) * 256 + threadIdx.x;
        if (i < NNODES) cnt[i] = 0;
        if (i < 16) S[i] = 0.0f;   // also zeroes the alpha-stats counter at ((int*)S)[15]
    }
}

__global__ void k_count(const int* __restrict__ dst, int* __restrict__ cnt) {
    int e = blockIdx.x * 256 + threadIdx.x;
    if (e < EEDGES) atomicAdd(&cnt[dst[e]], 1);
}

// ---------------- scan (+ fused dinv/cursor) ----------------
__global__ __launch_bounds__(1024) void k_scan(const int* __restrict__ cnt,
                                               int* __restrict__ rowptr,
                                               float* __restrict__ dinv,
                                               int* __restrict__ cursor) {
    __shared__ int sh[1024];
    int t = threadIdx.x;
    int base = t * 20;
    int local[20];
    int sum = 0;
#pragma unroll
    for (int j = 0; j < 20; j++) {
        int i = base + j;
        int v = (i < NNODES) ? cnt[i] : 0;
        if (i < NNODES) {
            dinv[i] = rsqrtf((float)v + 1.0f);
            cursor[i] = 0;
        }
        local[j] = sum;
        sum += v;
    }
    sh[t] = sum;
    __syncthreads();
    for (int off = 1; off < 1024; off <<= 1) {
        int v = (t >= off) ? sh[t - off] : 0;
        __syncthreads();
        sh[t] += v;
        __syncthreads();
    }
    int prev = (t > 0) ? sh[t - 1] : 0;
#pragma unroll
    for (int j = 0; j < 20; j++) {
        int i = base + j;
        if (i < NNODES) rowptr[i] = prev + local[j];
    }
    if (t == 1023) rowptr[NNODES] = sh[1023];
}

// ---------------- fused fill + GEMM1 ----------------
// blocks [0,1250): gemm1 (r1-verified 32x128 structure, byte-identical inner loop;
// ledger: 64x128=60, 32x128=48.8, 16x128/BK64=60.4, triple-buf=59, LDS-free=90.9).
// blocks [1250,2500): k_fill -- independent of gemm1, runs concurrently underneath it
// (fill is latency-bound scatter, gemm1 is compute; good co-residents).
__global__ __launch_bounds__(256) void k_fill_gemm1(const float* __restrict__ x,
                                                    const __bf16* __restrict__ Wtp,
                                                    __bf16* __restrict__ h0bf,
                                                    const int* __restrict__ src,
                                                    const int* __restrict__ dst,
                                                    const int* __restrict__ rowptr,
                                                    int* __restrict__ cursor,
                                                    const float* __restrict__ dinv,
                                                    int* __restrict__ srcsorted,
                                                    float* __restrict__ wsorted) {
    __shared__ __bf16 As[1024];   // 2 KB
    __shared__ __bf16 Bs[4096];   // 8 KB
    int b = blockIdx.x;
    if (b >= 1250) {
        int e = (b - 1250) * 256 + threadIdx.x;
        if (e < EEDGES) {
            int d = dst[e];
            int s = src[e];
            int pos = atomicAdd(&cursor[d], 1);
            int w = rowptr[d] + pos;
            srcsorted[w] = s;
            wsorted[w] = dinv[s];
        }
        return;
    }
    int t = threadIdx.x;
    int lane = t & 63;
    int m = lane & 15, q = lane >> 4;
    int w = t >> 6;
    int wc = w * 32;
    int r0 = (b >> 1) * 32;
    int h = b & 1;
    int c0 = h * 128;

    int arow = t >> 3;
    const float* ap = x + (size_t)(r0 + arow) * FIN + (t & 7) * 4;
    __bf16* awr = &As[arow * 32 + ((t & 7) >> 1) * 8 + (t & 1) * 4];
    const __bf16* bb = Wtp + (size_t)h * 4096;

    f32x4 acc[2][2] = {};

    float4 a = *(const float4*)(ap);

#pragma unroll 1
    for (int kk = 0; kk < 32; kk++) {
        async_copy16(bb + (size_t)kk * 8192 + t * 8, &Bs[t * 8]);
        async_copy16(bb + (size_t)kk * 8192 + (t + 256) * 8, &Bs[(t + 256) * 8]);
        bf16x4 av;
        av[0] = (__bf16)a.x; av[1] = (__bf16)a.y; av[2] = (__bf16)a.z; av[3] = (__bf16)a.w;
        *(bf16x4*)awr = av;
        if (kk + 1 < 32) a = *(const float4*)(ap + (kk + 1) * 32);
        __syncthreads();

        bf16x8 af[2], bfr[2];
#pragma unroll
        for (int i = 0; i < 2; i++)
            af[i] = *(const bf16x8*)&As[(i * 16 + m) * 32 + q * 8];
#pragma unroll
        for (int jb = 0; jb < 2; jb++)
            bfr[jb] = *(const bf16x8*)&Bs[(q * 128 + wc + jb * 16 + m) * 8];
#pragma unroll
        for (int i = 0; i < 2; i++)
#pragma unroll
            for (int jb = 0; jb < 2; jb++)
                acc[i][jb] = __builtin_amdgcn_mfma_f32_16x16x32_bf16(af[i], bfr[jb], acc[i][jb], 0, 0, 0);
        __syncthreads();
    }

#pragma unroll
    for (int i = 0; i < 2; i++)
#pragma unroll
        for (int jb = 0; jb < 2; jb++)
#pragma unroll
            for (int r = 0; r < 4; r++) {
                int row = r0 + i * 16 + q * 4 + r;
                int col = c0 + wc + jb * 16 + m;
                h0bf[(size_t)row * 256 + col] = (__bf16)acc[i][jb][r];
            }
}

// ---------------- GCN gather ----------------
__global__ __launch_bounds__(256) void k_gcn_gather(const int* __restrict__ rowptr,
                                                    const int* __restrict__ srcsorted,
                                                    const float* __restrict__ wsorted,
                                                    const __bf16* __restrict__ h0bf,
                                                    const float* __restrict__ dinv,
                                                    const float* __restrict__ bgcn,
                                                    __bf16* __restrict__ hbf) {
    int gid = blockIdx.x * 256 + threadIdx.x;
    int n = gid >> 6, l = gid & 63;
    if (n >= NNODES) return;
    float dn = dinv[n];
    float wn = dn * dn;
    bf16x4 hv = *(const bf16x4*)(h0bf + (size_t)n * 256 + l * 4);
    float4 b = ((const float4*)bgcn)[l];
    float ax = (float)hv[0] * wn + b.x;
    float ay = (float)hv[1] * wn + b.y;
    float az = (float)hv[2] * wn + b.z;
    float aw = (float)hv[3] * wn + b.w;
    int beg = rowptr[n], end = rowptr[n + 1];
    int deg = end - beg;
    int degc = deg < 64 ? deg : 64;

    int sidx = 0; float swt = 0.f;
    if (l < degc) {
        sidx = srcsorted[beg + l];
        swt = wsorted[beg + l] * dn;
    }

    for (int e0 = 0; e0 < degc; e0 += 8) {
#pragma unroll
        for (int j = 0; j < 8; j++) {
            int e = e0 + j;
            if (e >= degc) break;                       // wave-uniform
            int s = __builtin_amdgcn_readlane(sidx, e);
            float wv = readlane_f(swt, e);
            bf16x4 v = *(const bf16x4*)(h0bf + (size_t)s * 256 + l * 4);
            ax += (float)v[0] * wv;
            ay += (float)v[1] * wv;
            az += (float)v[2] * wv;
            aw += (float)v[3] * wv;
        }
    }
    for (int i = beg + 64; i < end; i++) {              // rare tail deg>64
        int s = srcsorted[i];
        float wv = wsorted[i] * dn;
        bf16x4 v = *(const bf16x4*)(h0bf + (size_t)s * 256 + l * 4);
        ax += (float)v[0] * wv;
        ay += (float)v[1] * wv;
        az += (float)v[2] * wv;
        aw += (float)v[3] * wv;
    }
    bf16x4 o;
    o[0] = (__bf16)(ax >= 0.f ? ax : 0.01f * ax);
    o[1] = (__bf16)(ay >= 0.f ? ay : 0.01f * ay);
    o[2] = (__bf16)(az >= 0.f ? az : 0.01f * az);
    o[3] = (__bf16)(aw >= 0.f ? aw : 0.01f * aw);
    *(bf16x4*)(hbf + (size_t)n * 256 + l * 4) = o;
}

// ---------------- GEMM2 (64x128 tile, 4.9 blocks/CU) ----------------
__global__ __launch_bounds__(256) void k_gemm2(const __bf16* __restrict__ hbf,
                                               const __bf16* __restrict__ Wallt,
                                               const float* __restrict__ ball,
                                               __bf16* __restrict__ qarr,
                                               __bf16* __restrict__ karr,
                                               __bf16* __restrict__ varr,
                                               __bf16* __restrict__ sarr) {
    __shared__ __bf16 As[2048];
    __shared__ __bf16 Bs[4096];
    int t = threadIdx.x;
    int lane = t & 63;
    int m = lane & 15, q = lane >> 4;
    int wave = t >> 6;
    int wr = (wave & 1) * 32;
    int wc = (wave >> 1) * 64;
    int r0 = blockIdx.x * 64;
    int c0 = blockIdx.y * 128;
    __bf16* tbl = (blockIdx.y == 0) ? qarr : (blockIdx.y == 1) ? karr
                : (blockIdx.y == 2) ? varr : sarr;

    int arow = r0 + (t & 63);
    if (arow >= NNODES) arow = NNODES - 1;
    const __bf16* asrc = hbf + (size_t)arow * HMID + (t >> 6) * 8;
    __bf16* aldst = &As[(size_t)t * 8];
    int u1 = t + 256;
    const __bf16* bsrc0 = Wallt + (size_t)(c0 + (t & 127)) * HMID + (t >> 7) * 8;
    __bf16* bldst0 = &Bs[(size_t)t * 8];
    const __bf16* bsrc1 = Wallt + (size_t)(c0 + (u1 & 127)) * HMID + (u1 >> 7) * 8;
    __bf16* bldst1 = &Bs[(size_t)u1 * 8];

    f32x4 acc[2][4] = {};

    for (int k0 = 0; k0 < HMID; k0 += 32) {
        async_copy16(asrc + k0, aldst);
        async_copy16(bsrc0 + k0, bldst0);
        async_copy16(bsrc1 + k0, bldst1);
        __syncthreads();

        bf16x8 af[2], bfr[4];
#pragma unroll
        for (int i = 0; i < 2; i++)
            af[i] = *(const bf16x8*)&As[(size_t)(q * 64 + wr + i * 16 + m) * 8];
#pragma unroll
        for (int jb = 0; jb < 4; jb++)
            bfr[jb] = *(const bf16x8*)&Bs[(size_t)(q * 128 + wc + jb * 16 + m) * 8];
#pragma unroll
        for (int i = 0; i < 2; i++)
#pragma unroll
            for (int jb = 0; jb < 4; jb++)
                acc[i][jb] = __builtin_amdgcn_mfma_f32_16x16x32_bf16(af[i], bfr[jb], acc[i][jb], 0, 0, 0);
        __syncthreads();
    }

#pragma unroll
    for (int jb = 0; jb < 4; jb++) {
        int dcol = wc + jb * 16 + m;
        float bias = ball[c0 + dcol];
#pragma unroll
        for (int i = 0; i < 2; i++)
#pragma unroll
            for (int r = 0; r < 4; r++) {
                int row = r0 + wr + i * 16 + q * 4 + r;
                if (row < NNODES) tbl[(size_t)row * 128 + dcol] = (__bf16)(acc[i][jb][r] + bias);
            }
    }
}

// ---------------- attention scores (+ fused last-block stats) ----------------
__global__ __launch_bounds__(256) void k_alpha(const int* __restrict__ rowptr,
                                               const int* __restrict__ srcsorted,
                                               const __bf16* __restrict__ qarr,
                                               const __bf16* __restrict__ karr,
                                               float* __restrict__ alpha,
                                               float* __restrict__ part,
                                               int* __restrict__ ctr,
                                               float* __restrict__ S) {
    int n = (blockIdx.x * 256 + threadIdx.x) >> 6;
    int lane = threadIdx.x & 63;
    int g = lane >> 4, l = lane & 15;
    float s1 = 0.f, s2 = 0.f;
    if (n < NNODES) {
        bf16x8 qb = *(const bf16x8*)(qarr + (size_t)n * 128 + l * 8);
        float qf[8];
#pragma unroll
        for (int j = 0; j < 8; j++) qf[j] = (float)qb[j];
        int beg = rowptr[n], end = rowptr[n + 1];
        for (int i = beg + g; i < end; i += 16) {
            int i1 = i + 4 < end ? i + 4 : end - 1;
            int i2 = i + 8 < end ? i + 8 : end - 1;
            int i3 = i + 12 < end ? i + 12 : end - 1;
            int s0 = srcsorted[i], sA = srcsorted[i1], sB = srcsorted[i2], sC = srcsorted[i3];
            bf16x8 k0 = *(const bf16x8*)(karr + (size_t)s0 * 128 + l * 8);
            bf16x8 k1 = *(const bf16x8*)(karr + (size_t)sA * 128 + l * 8);
            bf16x8 k2 = *(const bf16x8*)(karr + (size_t)sB * 128 + l * 8);
            bf16x8 k3 = *(const bf16x8*)(karr + (size_t)sC * 128 + l * 8);
            float d0 = 0.f, d1 = 0.f, d2 = 0.f, d3 = 0.f;
#pragma unroll
            for (int j = 0; j < 8; j++) {
                d0 += qf[j] * (float)k0[j];
                d1 += qf[j] * (float)k1[j];
                d2 += qf[j] * (float)k2[j];
                d3 += qf[j] * (float)k3[j];
            }
#pragma unroll
            for (int off = 1; off < 16; off <<= 1) {
                d0 += __shfl_xor(d0, off, 64);
                d1 += __shfl_xor(d1, off, 64);
                d2 += __shfl_xor(d2, off, 64);
                d3 += __shfl_xor(d3, off, 64);
            }
            if (l == 0) {
                const float sc = 0.08838834764831845f;
                float a0 = d0 * sc;
                alpha[i] = a0; s1 += a0; s2 += a0 * a0;
                if (i + 4 < end)  { float a = d1 * sc; alpha[i + 4]  = a; s1 += a; s2 += a * a; }
                if (i + 8 < end)  { float a = d2 * sc; alpha[i + 8]  = a; s1 += a; s2 += a * a; }
                if (i + 12 < end) { float a = d3 * sc; alpha[i + 12] = a; s1 += a; s2 += a * a; }
            }
        }
    }
#pragma unroll
    for (int off = 1; off < 64; off <<= 1) {
        s1 += __shfl_xor(s1, off, 64);
        s2 += __shfl_xor(s2, off, 64);
    }
    __shared__ float sh[8];
    __shared__ int lastFlag;
    int wave = threadIdx.x >> 6;
    if ((threadIdx.x & 63) == 0) { sh[wave] = s1; sh[4 + wave] = s2; }
    __syncthreads();
    if (threadIdx.x == 0) {
        part[2 * blockIdx.x]     = sh[0] + sh[1] + sh[2] + sh[3];
        part[2 * blockIdx.x + 1] = sh[4] + sh[5] + sh[6] + sh[7];
        __threadfence();
        int prev = atomicAdd(ctr, 1);
        lastFlag = (prev == ALPHA_BLOCKS - 1) ? 1 : 0;
    }
    __syncthreads();
    if (lastFlag) {
        __threadfence();
        float t1 = 0.f, t2 = 0.f;
        for (int i = threadIdx.x; i < ALPHA_BLOCKS; i += 256) {
            t1 += part[2 * i];
            t2 += part[2 * i + 1];
        }
#pragma unroll
        for (int off = 1; off < 64; off <<= 1) {
            t1 += __shfl_xor(t1, off, 64);
            t2 += __shfl_xor(t2, off, 64);
        }
        __syncthreads();   // sh reuse
        if ((threadIdx.x & 63) == 0) { sh[wave] = t1; sh[4 + wave] = t2; }
        __syncthreads();
        if (threadIdx.x == 0) {
            float u1 = sh[0] + sh[1] + sh[2] + sh[3];
            float u2 = sh[4] + sh[5] + sh[6] + sh[7];
            float mean = u1 / (float)EEDGES;
            float var = (u2 - (float)EEDGES * mean * mean) / (float)(EEDGES - 1);
            float stdv = sqrtf(fmaxf(var, 1e-20f));
            S[2] = mean;
            S[3] = 3.0f / stdv;
        }
    }
}

// ---------------- output gather ----------------
__global__ __launch_bounds__(256) void k_msg_gather(const int* __restrict__ rowptr,
                                                    const int* __restrict__ srcsorted,
                                                    const __bf16* __restrict__ varr,
                                                    const __bf16* __restrict__ sarr,
                                                    const float* __restrict__ alpha,
                                                    const float* __restrict__ S,
                                                    float* __restrict__ out) {
    int n = (blockIdx.x * 256 + threadIdx.x) >> 6;
    int l = threadIdx.x & 63;
    if (n >= NNODES) return;
    float mean = S[2], scl = S[3];
    bf16x2 sb = *(const bf16x2*)(sarr + (size_t)n * 128 + l * 2);
    float ax = (float)sb[0], ay = (float)sb[1];
    int beg = rowptr[n], end = rowptr[n + 1];
    int deg = end - beg;
    int degc = deg < 64 ? deg : 64;

    int sidx = 0; float gate = 0.f;
    if (l < degc) {
        sidx = srcsorted[beg + l];
        float z = (alpha[beg + l] - mean) * scl;
        gate = 1.0f / (1.0f + __expf(-z));
    }

    for (int e0 = 0; e0 < degc; e0 += 8) {
#pragma unroll
        for (int j = 0; j < 8; j++) {
            int e = e0 + j;
            if (e >= degc) break;                       // wave-uniform
            int s = __builtin_amdgcn_readlane(sidx, e);
            float gv = readlane_f(gate, e);
            bf16x2 v = *(const bf16x2*)(varr + (size_t)s * 128 + l * 2);
            ax += (float)v[0] * gv;
            ay += (float)v[1] * gv;
        }
    }
    for (int i = beg + 64; i < end; i++) {              // rare tail deg>64
        int s = srcsorted[i];
        float z = (alpha[i] - mean) * scl;
        float gv = 1.0f / (1.0f + __expf(-z));
        bf16x2 v = *(const bf16x2*)(varr + (size_t)s * 128 + l * 2);
        ax += (float)v[0] * gv;
        ay += (float)v[1] * gv;
    }
    float2 o; o.x = ax; o.y = ay;
    ((float2*)(out + (size_t)n * DOUT))[l] = o;
}

// ---------------- launch ----------------
extern "C" void kernel_launch(void* const* d_in, const int* in_sizes, int n_in,
                              void* d_out, int out_size, void* d_ws, size_t ws_size,
                              hipStream_t stream) {
    const float* x  = (const float*)d_in[0];
    const int* ei   = (const int*)d_in[1];
    const int* srcI = ei;
    const int* dstI = ei + EEDGES;
    const float* Wg = (const float*)d_in[2];
    const float* bg = (const float*)d_in[3];
    const float* Wq = (const float*)d_in[4];  const float* bq = (const float*)d_in[5];
    const float* Wk = (const float*)d_in[6];  const float* bk = (const float*)d_in[7];
    const float* Wv = (const float*)d_in[8];  const float* bv = (const float*)d_in[9];
    const float* Ws = (const float*)d_in[10]; const float* bs = (const float*)d_in[11];
    float* out = (float*)d_out;

    char* wsb = (char*)d_ws;
    size_t off = 0;
    auto alloc = [&](size_t bytes) -> void* {
        void* p = wsb + off;
        off += (bytes + 255) & ~(size_t)255;
        return p;
    };
    int*    cnt    = (int*)alloc((size_t)NNODES * 4);
    int*    rowptr = (int*)alloc((size_t)(NNODES + 1) * 4);
    int*    cursor = (int*)alloc((size_t)NNODES * 4);
    int*    srcst  = (int*)alloc((size_t)EEDGES * 4);
    float*  wsort  = (float*)alloc((size_t)EEDGES * 4);
    float*  dinv   = (float*)alloc((size_t)NNODES * 4);
    float*  S      = (float*)alloc(64);
    float*  part   = (float*)alloc((size_t)ALPHA_BLOCKS * 2 * 4);
    __bf16* Wtp    = (__bf16*)alloc((size_t)32 * 8192 * 2);
    __bf16* Wallt  = (__bf16*)alloc((size_t)512 * HMID * 2);
    float*  ball   = (float*)alloc(512 * 4);
    __bf16* h0bf   = (__bf16*)alloc((size_t)NNODES * HMID * 2);
    __bf16* hbf    = (__bf16*)alloc((size_t)NNODES * HMID * 2);
    __bf16* qarr   = (__bf16*)alloc((size_t)NNODES * 128 * 2);
    __bf16* karr   = (__bf16*)alloc((size_t)NNODES * 128 * 2);
    __bf16* varr   = (__bf16*)alloc((size_t)NNODES * 128 * 2);
    __bf16* sarr   = (__bf16*)alloc((size_t)NNODES * 128 * 2);
    float*  alphab = (float*)alloc((size_t)EEDGES * 4);
    if (off > ws_size) return;

    k_prep<<<271, 256, 0, stream>>>(Wg, Wq, Wk, Wv, Ws, bq, bk, bv, bs,
                                    Wtp, Wallt, ball, cnt, S);
    k_count<<<1250, 256, 0, stream>>>(dstI, cnt);
    k_scan<<<1, 1024, 0, stream>>>(cnt, rowptr, dinv, cursor);

    k_fill_gemm1<<<2500, 256, 0, stream>>>(x, Wtp, h0bf, srcI, dstI, rowptr, cursor,
                                           dinv, srcst, wsort);

    k_gcn_gather<<<5000, 256, 0, stream>>>(rowptr, srcst, wsort, h0bf, dinv, bg, hbf);

    dim3 g2(313, 4);
    k_gemm2<<<g2, 256, 0, stream>>>(hbf, Wallt, ball, qarr, karr, varr, sarr);

    k_alpha<<<ALPHA_BLOCKS, 256, 0, stream>>>(rowptr, srcst, qarr, karr, alphab, part,
                                              (int*)S + 15, S);

    k_msg_gather<<<5000, 256, 0, stream>>>(rowptr, srcst, varr, sarr, alphab, S, out);
}

// Round 9
// 350.867 us; speedup vs baseline: 1.3060x; 1.3060x over previous
//
#include <hip/hip_runtime.h>
#include <hip/hip_bf16.h>

#define NNODES 20000
#define EEDGES 320000
#define FIN 1024
#define HMID 256
#define DOUT 128
#define ALPHA_BLOCKS ((NNODES + 3) / 4)

typedef __bf16 bf16x8 __attribute__((ext_vector_type(8)));
typedef __bf16 bf16x4 __attribute__((ext_vector_type(4)));
typedef __bf16 bf16x2 __attribute__((ext_vector_type(2)));
typedef float f32x4 __attribute__((ext_vector_type(4)));

typedef const __attribute__((address_space(1))) void* gas_ptr;
typedef __attribute__((address_space(3))) void* las_ptr;
__device__ __forceinline__ void async_copy16(const void* g, void* l) {
    __builtin_amdgcn_global_load_lds((gas_ptr)g, (las_ptr)l, 16, 0, 0);
}

__device__ __forceinline__ float readlane_f(float v, int lane) {
    return __uint_as_float(__builtin_amdgcn_readlane(__float_as_uint(v), lane));
}

// ---------------- fused prep: pack_w + prep_watt + init (safe fusion, kept) ----------------
__global__ __launch_bounds__(256) void k_prep(const float* __restrict__ Wg,
                                              const float* __restrict__ Wq, const float* __restrict__ Wk,
                                              const float* __restrict__ Wv, const float* __restrict__ Ws,
                                              const float* __restrict__ bq, const float* __restrict__ bk,
                                              const float* __restrict__ bv, const float* __restrict__ bs,
                                              __bf16* __restrict__ Wtp, __bf16* __restrict__ Wallt,
                                              float* __restrict__ ball,
                                              int* __restrict__ cnt, float* __restrict__ S) {
    int b = blockIdx.x;
    if (b < 128) {
        int tid = b * 256 + threadIdx.x;   // 32768 units
        int kk = tid >> 10;
        int rem = tid & 1023;
        int h = rem >> 9;
        int u = rem & 511;
        int kq = u >> 7, c = u & 127;
        int col = h * 128 + c;
        int k0 = kk * 32 + kq * 8;
        bf16x8 v;
#pragma unroll
        for (int j = 0; j < 8; j++)
            v[j] = (__bf16)Wg[(size_t)(k0 + j) * HMID + col];
        *(bf16x8*)(Wtp + (size_t)tid * 8) = v;
    } else if (b < 192) {
        int g = (b - 128) >> 4;
        const float* W = (g == 0) ? Wq : (g == 1) ? Wk : (g == 2) ? Wv : Ws;
        int tid = ((b - 128) & 15) * 256 + threadIdx.x;   // 4096 units
        int n = tid & 127;
        int k0u = tid >> 7;
        bf16x8 v;
#pragma unroll
        for (int j = 0; j < 8; j++)
            v[j] = (__bf16)W[(size_t)(k0u * 8 + j) * DOUT + n];
        *(bf16x8*)(Wallt + (size_t)(g * DOUT + n) * HMID + k0u * 8) = v;
        if (tid < DOUT) {
            const float* bb = (g == 0) ? bq : (g == 1) ? bk : (g == 2) ? bv : bs;
            ball[g * DOUT + tid] = bb[tid];
        }
    } else {
        int i = (b - 192) * 256 + threadIdx.x;
        if (i < NNODES) cnt[i] = 0;
        if (i < 16) S[i] = 0.0f;
    }
}

__global__ void k_count(const int* __restrict__ dst, int* __restrict__ cnt) {
    int e = blockIdx.x * 256 + threadIdx.x;
    if (e < EEDGES) atomicAdd(&cnt[dst[e]], 1);
}

// ---------------- scan (+ fused dinv/cursor, safe fusion, kept) ----------------
__global__ __launch_bounds__(1024) void k_scan(const int* __restrict__ cnt,
                                               int* __restrict__ rowptr,
                                               float* __restrict__ dinv,
                                               int* __restrict__ cursor) {
    __shared__ int sh[1024];
    int t = threadIdx.x;
    int base = t * 20;
    int local[20];
    int sum = 0;
#pragma unroll
    for (int j = 0; j < 20; j++) {
        int i = base + j;
        int v = (i < NNODES) ? cnt[i] : 0;
        if (i < NNODES) {
            dinv[i] = rsqrtf((float)v + 1.0f);
            cursor[i] = 0;
        }
        local[j] = sum;
        sum += v;
    }
    sh[t] = sum;
    __syncthreads();
    for (int off = 1; off < 1024; off <<= 1) {
        int v = (t >= off) ? sh[t - off] : 0;
        __syncthreads();
        sh[t] += v;
        __syncthreads();
    }
    int prev = (t > 0) ? sh[t - 1] : 0;
#pragma unroll
    for (int j = 0; j < 20; j++) {
        int i = base + j;
        if (i < NNODES) rowptr[i] = prev + local[j];
    }
    if (t == 1023) rowptr[NNODES] = sh[1023];
}

// ---------------- fill (separate again: r8 fusion into gemm1 cost ~+35us) ----------------
__global__ void k_fill(const int* __restrict__ src, const int* __restrict__ dst,
                       const int* __restrict__ rowptr, int* __restrict__ cursor,
                       const float* __restrict__ dinv,
                       int* __restrict__ srcsorted, float* __restrict__ wsorted) {
    int e = blockIdx.x * 256 + threadIdx.x;
    if (e >= EEDGES) return;
    int d = dst[e];
    int s = src[e];
    int pos = atomicAdd(&cursor[d], 1);
    int w = rowptr[d] + pos;
    srcsorted[w] = s;
    wsorted[w] = dinv[s];
}

// ---------------- GEMM1 (r1-verified best, byte-identical) ----------------
__global__ __launch_bounds__(256) void k_gemm1(const float* __restrict__ x,
                                               const __bf16* __restrict__ Wtp,
                                               __bf16* __restrict__ h0bf) {
    __shared__ __bf16 As[1024];
    __shared__ __bf16 Bs[4096];
    int t = threadIdx.x;
    int lane = t & 63;
    int m = lane & 15, q = lane >> 4;
    int w = t >> 6;
    int wc = w * 32;
    int r0 = blockIdx.x * 32;
    int h = blockIdx.y;
    int c0 = h * 128;

    int arow = t >> 3;
    const float* ap = x + (size_t)(r0 + arow) * FIN + (t & 7) * 4;
    __bf16* awr = &As[arow * 32 + ((t & 7) >> 1) * 8 + (t & 1) * 4];
    const __bf16* bb = Wtp + (size_t)h * 4096;

    f32x4 acc[2][2] = {};

    float4 a = *(const float4*)(ap);

#pragma unroll 1
    for (int kk = 0; kk < 32; kk++) {
        async_copy16(bb + (size_t)kk * 8192 + t * 8, &Bs[t * 8]);
        async_copy16(bb + (size_t)kk * 8192 + (t + 256) * 8, &Bs[(t + 256) * 8]);
        bf16x4 av;
        av[0] = (__bf16)a.x; av[1] = (__bf16)a.y; av[2] = (__bf16)a.z; av[3] = (__bf16)a.w;
        *(bf16x4*)awr = av;
        if (kk + 1 < 32) a = *(const float4*)(ap + (kk + 1) * 32);
        __syncthreads();

        bf16x8 af[2], bfr[2];
#pragma unroll
        for (int i = 0; i < 2; i++)
            af[i] = *(const bf16x8*)&As[(i * 16 + m) * 32 + q * 8];
#pragma unroll
        for (int jb = 0; jb < 2; jb++)
            bfr[jb] = *(const bf16x8*)&Bs[(q * 128 + wc + jb * 16 + m) * 8];
#pragma unroll
        for (int i = 0; i < 2; i++)
#pragma unroll
            for (int jb = 0; jb < 2; jb++)
                acc[i][jb] = __builtin_amdgcn_mfma_f32_16x16x32_bf16(af[i], bfr[jb], acc[i][jb], 0, 0, 0);
        __syncthreads();
    }

#pragma unroll
    for (int i = 0; i < 2; i++)
#pragma unroll
        for (int jb = 0; jb < 2; jb++)
#pragma unroll
            for (int r = 0; r < 4; r++) {
                int row = r0 + i * 16 + q * 4 + r;
                int col = c0 + wc + jb * 16 + m;
                h0bf[(size_t)row * 256 + col] = (__bf16)acc[i][jb][r];
            }
}

// ---------------- GCN gather, half-column pass ----------------
// ch selects cols [ch*128, ch*128+128). Working set per pass = 5MB of distinct
// 128B lines (~ per-XCD L2 size) vs 10MB for the full-row version -> row re-touches
// (in-degree ~16) hit L2 instead of falling to L3. Two serial dispatches.
__global__ __launch_bounds__(256) void k_gcn_gather(const int* __restrict__ rowptr,
                                                    const int* __restrict__ srcsorted,
                                                    const float* __restrict__ wsorted,
                                                    const __bf16* __restrict__ h0bf,
                                                    const float* __restrict__ dinv,
                                                    const float* __restrict__ bgcn,
                                                    __bf16* __restrict__ hbf,
                                                    int ch) {
    int gid = blockIdx.x * 256 + threadIdx.x;
    int n = gid >> 6, l = gid & 63;
    if (n >= NNODES) return;
    float dn = dinv[n];
    float wn = dn * dn;
    int cb = ch * 128 + l * 2;
    bf16x2 hv = *(const bf16x2*)(h0bf + (size_t)n * 256 + cb);
    float2 b = ((const float2*)bgcn)[ch * 64 + l];
    float ax = (float)hv[0] * wn + b.x;
    float ay = (float)hv[1] * wn + b.y;
    int beg = rowptr[n], end = rowptr[n + 1];
    int deg = end - beg;
    int degc = deg < 64 ? deg : 64;

    int sidx = 0; float swt = 0.f;
    if (l < degc) {
        sidx = srcsorted[beg + l];
        swt = wsorted[beg + l] * dn;
    }

    for (int e0 = 0; e0 < degc; e0 += 8) {
#pragma unroll
        for (int j = 0; j < 8; j++) {
            int e = e0 + j;
            if (e >= degc) break;                       // wave-uniform
            int s = __builtin_amdgcn_readlane(sidx, e);
            float wv = readlane_f(swt, e);
            bf16x2 v = *(const bf16x2*)(h0bf + (size_t)s * 256 + cb);
            ax += (float)v[0] * wv;
            ay += (float)v[1] * wv;
        }
    }
    for (int i = beg + 64; i < end; i++) {              // rare tail deg>64
        int s = srcsorted[i];
        float wv = wsorted[i] * dn;
        bf16x2 v = *(const bf16x2*)(h0bf + (size_t)s * 256 + cb);
        ax += (float)v[0] * wv;
        ay += (float)v[1] * wv;
    }
    bf16x2 o;
    o[0] = (__bf16)(ax >= 0.f ? ax : 0.01f * ax);
    o[1] = (__bf16)(ay >= 0.f ? ay : 0.01f * ay);
    *(bf16x2*)(hbf + (size_t)n * 256 + cb) = o;
}

// ---------------- GEMM2 (64x128 tile, 4.9 blocks/CU) ----------------
__global__ __launch_bounds__(256) void k_gemm2(const __bf16* __restrict__ hbf,
                                               const __bf16* __restrict__ Wallt,
                                               const float* __restrict__ ball,
                                               __bf16* __restrict__ qarr,
                                               __bf16* __restrict__ karr,
                                               __bf16* __restrict__ varr,
                                               __bf16* __restrict__ sarr) {
    __shared__ __bf16 As[2048];
    __shared__ __bf16 Bs[4096];
    int t = threadIdx.x;
    int lane = t & 63;
    int m = lane & 15, q = lane >> 4;
    int wave = t >> 6;
    int wr = (wave & 1) * 32;
    int wc = (wave >> 1) * 64;
    int r0 = blockIdx.x * 64;
    int c0 = blockIdx.y * 128;
    __bf16* tbl = (blockIdx.y == 0) ? qarr : (blockIdx.y == 1) ? karr
                : (blockIdx.y == 2) ? varr : sarr;

    int arow = r0 + (t & 63);
    if (arow >= NNODES) arow = NNODES - 1;
    const __bf16* asrc = hbf + (size_t)arow * HMID + (t >> 6) * 8;
    __bf16* aldst = &As[(size_t)t * 8];
    int u1 = t + 256;
    const __bf16* bsrc0 = Wallt + (size_t)(c0 + (t & 127)) * HMID + (t >> 7) * 8;
    __bf16* bldst0 = &Bs[(size_t)t * 8];
    const __bf16* bsrc1 = Wallt + (size_t)(c0 + (u1 & 127)) * HMID + (u1 >> 7) * 8;
    __bf16* bldst1 = &Bs[(size_t)u1 * 8];

    f32x4 acc[2][4] = {};

    for (int k0 = 0; k0 < HMID; k0 += 32) {
        async_copy16(asrc + k0, aldst);
        async_copy16(bsrc0 + k0, bldst0);
        async_copy16(bsrc1 + k0, bldst1);
        __syncthreads();

        bf16x8 af[2], bfr[4];
#pragma unroll
        for (int i = 0; i < 2; i++)
            af[i] = *(const bf16x8*)&As[(size_t)(q * 64 + wr + i * 16 + m) * 8];
#pragma unroll
        for (int jb = 0; jb < 4; jb++)
            bfr[jb] = *(const bf16x8*)&Bs[(size_t)(q * 128 + wc + jb * 16 + m) * 8];
#pragma unroll
        for (int i = 0; i < 2; i++)
#pragma unroll
            for (int jb = 0; jb < 4; jb++)
                acc[i][jb] = __builtin_amdgcn_mfma_f32_16x16x32_bf16(af[i], bfr[jb], acc[i][jb], 0, 0, 0);
        __syncthreads();
    }

#pragma unroll
    for (int jb = 0; jb < 4; jb++) {
        int dcol = wc + jb * 16 + m;
        float bias = ball[c0 + dcol];
#pragma unroll
        for (int i = 0; i < 2; i++)
#pragma unroll
            for (int r = 0; r < 4; r++) {
                int row = r0 + wr + i * 16 + q * 4 + r;
                if (row < NNODES) tbl[(size_t)row * 128 + dcol] = (__bf16)(acc[i][jb][r] + bias);
            }
    }
}

// ---------------- attention scores (r7 version; r8's fused-fence variant cost +110us) ----------------
__global__ __launch_bounds__(256) void k_alpha(const int* __restrict__ rowptr,
                                               const int* __restrict__ srcsorted,
                                               const __bf16* __restrict__ qarr,
                                               const __bf16* __restrict__ karr,
                                               float* __restrict__ alpha,
                                               float* __restrict__ part) {
    int n = (blockIdx.x * 256 + threadIdx.x) >> 6;
    int lane = threadIdx.x & 63;
    int g = lane >> 4, l = lane & 15;
    float s1 = 0.f, s2 = 0.f;
    if (n < NNODES) {
        bf16x8 qb = *(const bf16x8*)(qarr + (size_t)n * 128 + l * 8);
        float qf[8];
#pragma unroll
        for (int j = 0; j < 8; j++) qf[j] = (float)qb[j];
        int beg = rowptr[n], end = rowptr[n + 1];
        for (int i = beg + g; i < end; i += 16) {
            int i1 = i + 4 < end ? i + 4 : end - 1;
            int i2 = i + 8 < end ? i + 8 : end - 1;
            int i3 = i + 12 < end ? i + 12 : end - 1;
            int s0 = srcsorted[i], sA = srcsorted[i1], sB = srcsorted[i2], sC = srcsorted[i3];
            bf16x8 k0 = *(const bf16x8*)(karr + (size_t)s0 * 128 + l * 8);
            bf16x8 k1 = *(const bf16x8*)(karr + (size_t)sA * 128 + l * 8);
            bf16x8 k2 = *(const bf16x8*)(karr + (size_t)sB * 128 + l * 8);
            bf16x8 k3 = *(const bf16x8*)(karr + (size_t)sC * 128 + l * 8);
            float d0 = 0.f, d1 = 0.f, d2 = 0.f, d3 = 0.f;
#pragma unroll
            for (int j = 0; j < 8; j++) {
                d0 += qf[j] * (float)k0[j];
                d1 += qf[j] * (float)k1[j];
                d2 += qf[j] * (float)k2[j];
                d3 += qf[j] * (float)k3[j];
            }
#pragma unroll
            for (int off = 1; off < 16; off <<= 1) {
                d0 += __shfl_xor(d0, off, 64);
                d1 += __shfl_xor(d1, off, 64);
                d2 += __shfl_xor(d2, off, 64);
                d3 += __shfl_xor(d3, off, 64);
            }
            if (l == 0) {
                const float sc = 0.08838834764831845f;
                float a0 = d0 * sc;
                alpha[i] = a0; s1 += a0; s2 += a0 * a0;
                if (i + 4 < end)  { float a = d1 * sc; alpha[i + 4]  = a; s1 += a; s2 += a * a; }
                if (i + 8 < end)  { float a = d2 * sc; alpha[i + 8]  = a; s1 += a; s2 += a * a; }
                if (i + 12 < end) { float a = d3 * sc; alpha[i + 12] = a; s1 += a; s2 += a * a; }
            }
        }
    }
#pragma unroll
    for (int off = 1; off < 64; off <<= 1) {
        s1 += __shfl_xor(s1, off, 64);
        s2 += __shfl_xor(s2, off, 64);
    }
    __shared__ float sh[8];
    int wave = threadIdx.x >> 6;
    if ((threadIdx.x & 63) == 0) { sh[wave] = s1; sh[4 + wave] = s2; }
    __syncthreads();
    if (threadIdx.x == 0) {
        part[2 * blockIdx.x]     = sh[0] + sh[1] + sh[2] + sh[3];
        part[2 * blockIdx.x + 1] = sh[4] + sh[5] + sh[6] + sh[7];
    }
}

__global__ __launch_bounds__(1024) void k_stats(const float* __restrict__ part,
                                                float* __restrict__ S) {
    float s1 = 0.f, s2 = 0.f;
    for (int i = threadIdx.x; i < ALPHA_BLOCKS; i += 1024) {
        s1 += part[2 * i];
        s2 += part[2 * i + 1];
    }
#pragma unroll
    for (int off = 1; off < 64; off <<= 1) {
        s1 += __shfl_xor(s1, off, 64);
        s2 += __shfl_xor(s2, off, 64);
    }
    __shared__ float sh1[16], sh2[16];
    int wave = threadIdx.x >> 6;
    if ((threadIdx.x & 63) == 0) { sh1[wave] = s1; sh2[wave] = s2; }
    __syncthreads();
    if (threadIdx.x == 0) {
        float t1 = 0.f, t2 = 0.f;
#pragma unroll
        for (int w = 0; w < 16; w++) { t1 += sh1[w]; t2 += sh2[w]; }
        float mean = t1 / (float)EEDGES;
        float var = (t2 - (float)EEDGES * mean * mean) / (float)(EEDGES - 1);
        float stdv = sqrtf(fmaxf(var, 1e-20f));
        S[2] = mean;
        S[3] = 3.0f / stdv;
    }
}

// ---------------- output gather (r7 version) ----------------
__global__ __launch_bounds__(256) void k_msg_gather(const int* __restrict__ rowptr,
                                                    const int* __restrict__ srcsorted,
                                                    const __bf16* __restrict__ varr,
                                                    const __bf16* __restrict__ sarr,
                                                    const float* __restrict__ alpha,
                                                    const float* __restrict__ S,
                                                    float* __restrict__ out) {
    int n = (blockIdx.x * 256 + threadIdx.x) >> 6;
    int l = threadIdx.x & 63;
    if (n >= NNODES) return;
    float mean = S[2], scl = S[3];
    bf16x2 sb = *(const bf16x2*)(sarr + (size_t)n * 128 + l * 2);
    float ax = (float)sb[0], ay = (float)sb[1];
    int beg = rowptr[n], end = rowptr[n + 1];
    int deg = end - beg;
    int degc = deg < 64 ? deg : 64;

    int sidx = 0; float gate = 0.f;
    if (l < degc) {
        sidx = srcsorted[beg + l];
        float z = (alpha[beg + l] - mean) * scl;
        gate = 1.0f / (1.0f + __expf(-z));
    }

    for (int e0 = 0; e0 < degc; e0 += 8) {
#pragma unroll
        for (int j = 0; j < 8; j++) {
            int e = e0 + j;
            if (e >= degc) break;                       // wave-uniform
            int s = __builtin_amdgcn_readlane(sidx, e);
            float gv = readlane_f(gate, e);
            bf16x2 v = *(const bf16x2*)(varr + (size_t)s * 128 + l * 2);
            ax += (float)v[0] * gv;
            ay += (float)v[1] * gv;
        }
    }
    for (int i = beg + 64; i < end; i++) {              // rare tail deg>64
        int s = srcsorted[i];
        float z = (alpha[i] - mean) * scl;
        float gv = 1.0f / (1.0f + __expf(-z));
        bf16x2 v = *(const bf16x2*)(varr + (size_t)s * 128 + l * 2);
        ax += (float)v[0] * gv;
        ay += (float)v[1] * gv;
    }
    float2 o; o.x = ax; o.y = ay;
    ((float2*)(out + (size_t)n * DOUT))[l] = o;
}

// ---------------- launch ----------------
extern "C" void kernel_launch(void* const* d_in, const int* in_sizes, int n_in,
                              void* d_out, int out_size, void* d_ws, size_t ws_size,
                              hipStream_t stream) {
    const float* x  = (const float*)d_in[0];
    const int* ei   = (const int*)d_in[1];
    const int* srcI = ei;
    const int* dstI = ei + EEDGES;
    const float* Wg = (const float*)d_in[2];
    const float* bg = (const float*)d_in[3];
    const float* Wq = (const float*)d_in[4];  const float* bq = (const float*)d_in[5];
    const float* Wk = (const float*)d_in[6];  const float* bk = (const float*)d_in[7];
    const float* Wv = (const float*)d_in[8];  const float* bv = (const float*)d_in[9];
    const float* Ws = (const float*)d_in[10]; const float* bs = (const float*)d_in[11];
    float* out = (float*)d_out;

    char* wsb = (char*)d_ws;
    size_t off = 0;
    auto alloc = [&](size_t bytes) -> void* {
        void* p = wsb + off;
        off += (bytes + 255) & ~(size_t)255;
        return p;
    };
    int*    cnt    = (int*)alloc((size_t)NNODES * 4);
    int*    rowptr = (int*)alloc((size_t)(NNODES + 1) * 4);
    int*    cursor = (int*)alloc((size_t)NNODES * 4);
    int*    srcst  = (int*)alloc((size_t)EEDGES * 4);
    float*  wsort  = (float*)alloc((size_t)EEDGES * 4);
    float*  dinv   = (float*)alloc((size_t)NNODES * 4);
    float*  S      = (float*)alloc(64);
    float*  part   = (float*)alloc((size_t)ALPHA_BLOCKS * 2 * 4);
    __bf16* Wtp    = (__bf16*)alloc((size_t)32 * 8192 * 2);
    __bf16* Wallt  = (__bf16*)alloc((size_t)512 * HMID * 2);
    float*  ball   = (float*)alloc(512 * 4);
    __bf16* h0bf   = (__bf16*)alloc((size_t)NNODES * HMID * 2);
    __bf16* hbf    = (__bf16*)alloc((size_t)NNODES * HMID * 2);
    __bf16* qarr   = (__bf16*)alloc((size_t)NNODES * 128 * 2);
    __bf16* karr   = (__bf16*)alloc((size_t)NNODES * 128 * 2);
    __bf16* varr   = (__bf16*)alloc((size_t)NNODES * 128 * 2);
    __bf16* sarr   = (__bf16*)alloc((size_t)NNODES * 128 * 2);
    float*  alphab = (float*)alloc((size_t)EEDGES * 4);
    if (off > ws_size) return;

    k_prep<<<271, 256, 0, stream>>>(Wg, Wq, Wk, Wv, Ws, bq, bk, bv, bs,
                                    Wtp, Wallt, ball, cnt, S);
    k_count<<<1250, 256, 0, stream>>>(dstI, cnt);
    k_scan<<<1, 1024, 0, stream>>>(cnt, rowptr, dinv, cursor);
    k_fill<<<1250, 256, 0, stream>>>(srcI, dstI, rowptr, cursor, dinv, srcst, wsort);

    dim3 g1(625, 2);
    k_gemm1<<<g1, 256, 0, stream>>>(x, Wtp, h0bf);

    k_gcn_gather<<<5000, 256, 0, stream>>>(rowptr, srcst, wsort, h0bf, dinv, bg, hbf, 0);
    k_gcn_gather<<<5000, 256, 0, stream>>>(rowptr, srcst, wsort, h0bf, dinv, bg, hbf, 1);

    dim3 g2(313, 4);
    k_gemm2<<<g2, 256, 0, stream>>>(hbf, Wallt, ball, qarr, karr, varr, sarr);

    k_alpha<<<ALPHA_BLOCKS, 256, 0, stream>>>(rowptr, srcst, qarr, karr, alphab, part);
    k_stats<<<1, 1024, 0, stream>>>(part, S);

    k_msg_gather<<<5000, 256, 0, stream>>>(rowptr, srcst, varr, sarr, alphab, S, out);
}

// Round 10
// 316.681 us; speedup vs baseline: 1.4470x; 1.1080x over previous
//
#include <hip/hip_runtime.h>
#include <hip/hip_bf16.h>

#define NNODES 20000
#define EEDGES 320000
#define FIN 1024
#define HMID 256
#define DOUT 128
#define ALPHA_BLOCKS ((NNODES + 3) / 4)

typedef __bf16 bf16x8 __attribute__((ext_vector_type(8)));
typedef __bf16 bf16x4 __attribute__((ext_vector_type(4)));
typedef __bf16 bf16x2 __attribute__((ext_vector_type(2)));
typedef float f32x4 __attribute__((ext_vector_type(4)));

typedef const __attribute__((address_space(1))) void* gas_ptr;
typedef __attribute__((address_space(3))) void* las_ptr;
__device__ __forceinline__ void async_copy16(const void* g, void* l) {
    __builtin_amdgcn_global_load_lds((gas_ptr)g, (las_ptr)l, 16, 0, 0);
}

__device__ __forceinline__ float readlane_f(float v, int lane) {
    return __uint_as_float(__builtin_amdgcn_readlane(__float_as_uint(v), lane));
}

// ---------------- fused prep: pack_w + prep_watt + init (safe fusion, kept) ----------------
__global__ __launch_bounds__(256) void k_prep(const float* __restrict__ Wg,
                                              const float* __restrict__ Wq, const float* __restrict__ Wk,
                                              const float* __restrict__ Wv, const float* __restrict__ Ws,
                                              const float* __restrict__ bq, const float* __restrict__ bk,
                                              const float* __restrict__ bv, const float* __restrict__ bs,
                                              __bf16* __restrict__ Wtp, __bf16* __restrict__ Wallt,
                                              float* __restrict__ ball,
                                              int* __restrict__ cnt, float* __restrict__ S) {
    int b = blockIdx.x;
    if (b < 128) {
        int tid = b * 256 + threadIdx.x;   // 32768 units
        int kk = tid >> 10;
        int rem = tid & 1023;
        int h = rem >> 9;
        int u = rem & 511;
        int kq = u >> 7, c = u & 127;
        int col = h * 128 + c;
        int k0 = kk * 32 + kq * 8;
        bf16x8 v;
#pragma unroll
        for (int j = 0; j < 8; j++)
            v[j] = (__bf16)Wg[(size_t)(k0 + j) * HMID + col];
        *(bf16x8*)(Wtp + (size_t)tid * 8) = v;
    } else if (b < 192) {
        int g = (b - 128) >> 4;
        const float* W = (g == 0) ? Wq : (g == 1) ? Wk : (g == 2) ? Wv : Ws;
        int tid = ((b - 128) & 15) * 256 + threadIdx.x;   // 4096 units
        int n = tid & 127;
        int k0u = tid >> 7;
        bf16x8 v;
#pragma unroll
        for (int j = 0; j < 8; j++)
            v[j] = (__bf16)W[(size_t)(k0u * 8 + j) * DOUT + n];
        *(bf16x8*)(Wallt + (size_t)(g * DOUT + n) * HMID + k0u * 8) = v;
        if (tid < DOUT) {
            const float* bb = (g == 0) ? bq : (g == 1) ? bk : (g == 2) ? bv : bs;
            ball[g * DOUT + tid] = bb[tid];
        }
    } else {
        int i = (b - 192) * 256 + threadIdx.x;
        if (i < NNODES) cnt[i] = 0;
        if (i < 16) S[i] = 0.0f;
    }
}

// count: the atomicAdd return value IS the CSR slot -- record it so k_fill needs no atomic.
__global__ void k_count(const int* __restrict__ dst, int* __restrict__ cnt,
                        int* __restrict__ epos) {
    int e = blockIdx.x * 256 + threadIdx.x;
    if (e < EEDGES) epos[e] = atomicAdd(&cnt[dst[e]], 1);
}

// ---------------- scan (+ fused dinv, safe fusion, kept; cursor eliminated) ----------------
__global__ __launch_bounds__(1024) void k_scan(const int* __restrict__ cnt,
                                               int* __restrict__ rowptr,
                                               float* __restrict__ dinv) {
    __shared__ int sh[1024];
    int t = threadIdx.x;
    int base = t * 20;
    int local[20];
    int sum = 0;
#pragma unroll
    for (int j = 0; j < 20; j++) {
        int i = base + j;
        int v = (i < NNODES) ? cnt[i] : 0;
        if (i < NNODES) dinv[i] = rsqrtf((float)v + 1.0f);
        local[j] = sum;
        sum += v;
    }
    sh[t] = sum;
    __syncthreads();
    for (int off = 1; off < 1024; off <<= 1) {
        int v = (t >= off) ? sh[t - off] : 0;
        __syncthreads();
        sh[t] += v;
        __syncthreads();
    }
    int prev = (t > 0) ? sh[t - 1] : 0;
#pragma unroll
    for (int j = 0; j < 20; j++) {
        int i = base + j;
        if (i < NNODES) rowptr[i] = prev + local[j];
    }
    if (t == 1023) rowptr[NNODES] = sh[1023];
}

// ---------------- fill (atomic-free: slot = rowptr[d] + epos[e]) ----------------
__global__ void k_fill(const int* __restrict__ src, const int* __restrict__ dst,
                       const int* __restrict__ rowptr, const int* __restrict__ epos,
                       const float* __restrict__ dinv,
                       int* __restrict__ srcsorted, float* __restrict__ wsorted) {
    int e = blockIdx.x * 256 + threadIdx.x;
    if (e >= EEDGES) return;
    int d = dst[e];
    int s = src[e];
    int w = rowptr[d] + epos[e];
    srcsorted[w] = s;
    wsorted[w] = dinv[s];
}

// ---------------- GEMM1 (r1-verified best, byte-identical) ----------------
__global__ __launch_bounds__(256) void k_gemm1(const float* __restrict__ x,
                                               const __bf16* __restrict__ Wtp,
                                               __bf16* __restrict__ h0bf) {
    __shared__ __bf16 As[1024];
    __shared__ __bf16 Bs[4096];
    int t = threadIdx.x;
    int lane = t & 63;
    int m = lane & 15, q = lane >> 4;
    int w = t >> 6;
    int wc = w * 32;
    int r0 = blockIdx.x * 32;
    int h = blockIdx.y;
    int c0 = h * 128;

    int arow = t >> 3;
    const float* ap = x + (size_t)(r0 + arow) * FIN + (t & 7) * 4;
    __bf16* awr = &As[arow * 32 + ((t & 7) >> 1) * 8 + (t & 1) * 4];
    const __bf16* bb = Wtp + (size_t)h * 4096;

    f32x4 acc[2][2] = {};

    float4 a = *(const float4*)(ap);

#pragma unroll 1
    for (int kk = 0; kk < 32; kk++) {
        async_copy16(bb + (size_t)kk * 8192 + t * 8, &Bs[t * 8]);
        async_copy16(bb + (size_t)kk * 8192 + (t + 256) * 8, &Bs[(t + 256) * 8]);
        bf16x4 av;
        av[0] = (__bf16)a.x; av[1] = (__bf16)a.y; av[2] = (__bf16)a.z; av[3] = (__bf16)a.w;
        *(bf16x4*)awr = av;
        if (kk + 1 < 32) a = *(const float4*)(ap + (kk + 1) * 32);
        __syncthreads();

        bf16x8 af[2], bfr[2];
#pragma unroll
        for (int i = 0; i < 2; i++)
            af[i] = *(const bf16x8*)&As[(i * 16 + m) * 32 + q * 8];
#pragma unroll
        for (int jb = 0; jb < 2; jb++)
            bfr[jb] = *(const bf16x8*)&Bs[(q * 128 + wc + jb * 16 + m) * 8];
#pragma unroll
        for (int i = 0; i < 2; i++)
#pragma unroll
            for (int jb = 0; jb < 2; jb++)
                acc[i][jb] = __builtin_amdgcn_mfma_f32_16x16x32_bf16(af[i], bfr[jb], acc[i][jb], 0, 0, 0);
        __syncthreads();
    }

#pragma unroll
    for (int i = 0; i < 2; i++)
#pragma unroll
        for (int jb = 0; jb < 2; jb++)
#pragma unroll
            for (int r = 0; r < 4; r++) {
                int row = r0 + i * 16 + q * 4 + r;
                int col = c0 + wc + jb * 16 + m;
                h0bf[(size_t)row * 256 + col] = (__bf16)acc[i][jb][r];
            }
}

// ---------------- GCN gather (r7 v2: full-row bf16x4; r9's half-column split cost +36us
// -- 5MB half-pass working set still exceeds the 4MB per-XCD L2, so no hit-rate gain
// while doubling instructions. Do not re-split.) ----------------
__global__ __launch_bounds__(256) void k_gcn_gather(const int* __restrict__ rowptr,
                                                    const int* __restrict__ srcsorted,
                                                    const float* __restrict__ wsorted,
                                                    const __bf16* __restrict__ h0bf,
                                                    const float* __restrict__ dinv,
                                                    const float* __restrict__ bgcn,
                                                    __bf16* __restrict__ hbf) {
    int gid = blockIdx.x * 256 + threadIdx.x;
    int n = gid >> 6, l = gid & 63;
    if (n >= NNODES) return;
    float dn = dinv[n];
    float wn = dn * dn;
    bf16x4 hv = *(const bf16x4*)(h0bf + (size_t)n * 256 + l * 4);
    float4 b = ((const float4*)bgcn)[l];
    float ax = (float)hv[0] * wn + b.x;
    float ay = (float)hv[1] * wn + b.y;
    float az = (float)hv[2] * wn + b.z;
    float aw = (float)hv[3] * wn + b.w;
    int beg = rowptr[n], end = rowptr[n + 1];
    int deg = end - beg;
    int degc = deg < 64 ? deg : 64;

    int sidx = 0; float swt = 0.f;
    if (l < degc) {
        sidx = srcsorted[beg + l];
        swt = wsorted[beg + l] * dn;
    }

    for (int e0 = 0; e0 < degc; e0 += 8) {
#pragma unroll
        for (int j = 0; j < 8; j++) {
            int e = e0 + j;
            if (e >= degc) break;                       // wave-uniform
            int s = __builtin_amdgcn_readlane(sidx, e);
            float wv = readlane_f(swt, e);
            bf16x4 v = *(const bf16x4*)(h0bf + (size_t)s * 256 + l * 4);
            ax += (float)v[0] * wv;
            ay += (float)v[1] * wv;
            az += (float)v[2] * wv;
            aw += (float)v[3] * wv;
        }
    }
    for (int i = beg + 64; i < end; i++) {              // rare tail deg>64
        int s = srcsorted[i];
        float wv = wsorted[i] * dn;
        bf16x4 v = *(const bf16x4*)(h0bf + (size_t)s * 256 + l * 4);
        ax += (float)v[0] * wv;
        ay += (float)v[1] * wv;
        az += (float)v[2] * wv;
        aw += (float)v[3] * wv;
    }
    bf16x4 o;
    o[0] = (__bf16)(ax >= 0.f ? ax : 0.01f * ax);
    o[1] = (__bf16)(ay >= 0.f ? ay : 0.01f * ay);
    o[2] = (__bf16)(az >= 0.f ? az : 0.01f * az);
    o[3] = (__bf16)(aw >= 0.f ? aw : 0.01f * aw);
    *(bf16x4*)(hbf + (size_t)n * 256 + l * 4) = o;
}

// ---------------- GEMM2 (64x128 tile, 4.9 blocks/CU) ----------------
__global__ __launch_bounds__(256) void k_gemm2(const __bf16* __restrict__ hbf,
                                               const __bf16* __restrict__ Wallt,
                                               const float* __restrict__ ball,
                                               __bf16* __restrict__ qarr,
                                               __bf16* __restrict__ karr,
                                               __bf16* __restrict__ varr,
                                               __bf16* __restrict__ sarr) {
    __shared__ __bf16 As[2048];
    __shared__ __bf16 Bs[4096];
    int t = threadIdx.x;
    int lane = t & 63;
    int m = lane & 15, q = lane >> 4;
    int wave = t >> 6;
    int wr = (wave & 1) * 32;
    int wc = (wave >> 1) * 64;
    int r0 = blockIdx.x * 64;
    int c0 = blockIdx.y * 128;
    __bf16* tbl = (blockIdx.y == 0) ? qarr : (blockIdx.y == 1) ? karr
                : (blockIdx.y == 2) ? varr : sarr;

    int arow = r0 + (t & 63);
    if (arow >= NNODES) arow = NNODES - 1;
    const __bf16* asrc = hbf + (size_t)arow * HMID + (t >> 6) * 8;
    __bf16* aldst = &As[(size_t)t * 8];
    int u1 = t + 256;
    const __bf16* bsrc0 = Wallt + (size_t)(c0 + (t & 127)) * HMID + (t >> 7) * 8;
    __bf16* bldst0 = &Bs[(size_t)t * 8];
    const __bf16* bsrc1 = Wallt + (size_t)(c0 + (u1 & 127)) * HMID + (u1 >> 7) * 8;
    __bf16* bldst1 = &Bs[(size_t)u1 * 8];

    f32x4 acc[2][4] = {};

    for (int k0 = 0; k0 < HMID; k0 += 32) {
        async_copy16(asrc + k0, aldst);
        async_copy16(bsrc0 + k0, bldst0);
        async_copy16(bsrc1 + k0, bldst1);
        __syncthreads();

        bf16x8 af[2], bfr[4];
#pragma unroll
        for (int i = 0; i < 2; i++)
            af[i] = *(const bf16x8*)&As[(size_t)(q * 64 + wr + i * 16 + m) * 8];
#pragma unroll
        for (int jb = 0; jb < 4; jb++)
            bfr[jb] = *(const bf16x8*)&Bs[(size_t)(q * 128 + wc + jb * 16 + m) * 8];
#pragma unroll
        for (int i = 0; i < 2; i++)
#pragma unroll
            for (int jb = 0; jb < 4; jb++)
                acc[i][jb] = __builtin_amdgcn_mfma_f32_16x16x32_bf16(af[i], bfr[jb], acc[i][jb], 0, 0, 0);
        __syncthreads();
    }

#pragma unroll
    for (int jb = 0; jb < 4; jb++) {
        int dcol = wc + jb * 16 + m;
        float bias = ball[c0 + dcol];
#pragma unroll
        for (int i = 0; i < 2; i++)
#pragma unroll
            for (int r = 0; r < 4; r++) {
                int row = r0 + wr + i * 16 + q * 4 + r;
                if (row < NNODES) tbl[(size_t)row * 128 + dcol] = (__bf16)(acc[i][jb][r] + bias);
            }
    }
}

// ---------------- attention scores ----------------
__global__ __launch_bounds__(256) void k_alpha(const int* __restrict__ rowptr,
                                               const int* __restrict__ srcsorted,
                                               const __bf16* __restrict__ qarr,
                                               const __bf16* __restrict__ karr,
                                               float* __restrict__ alpha,
                                               float* __restrict__ part) {
    int n = (blockIdx.x * 256 + threadIdx.x) >> 6;
    int lane = threadIdx.x & 63;
    int g = lane >> 4, l = lane & 15;
    float s1 = 0.f, s2 = 0.f;
    if (n < NNODES) {
        bf16x8 qb = *(const bf16x8*)(qarr + (size_t)n * 128 + l * 8);
        float qf[8];
#pragma unroll
        for (int j = 0; j < 8; j++) qf[j] = (float)qb[j];
        int beg = rowptr[n], end = rowptr[n + 1];
        for (int i = beg + g; i < end; i += 16) {
            int i1 = i + 4 < end ? i + 4 : end - 1;
            int i2 = i + 8 < end ? i + 8 : end - 1;
            int i3 = i + 12 < end ? i + 12 : end - 1;
            int s0 = srcsorted[i], sA = srcsorted[i1], sB = srcsorted[i2], sC = srcsorted[i3];
            bf16x8 k0 = *(const bf16x8*)(karr + (size_t)s0 * 128 + l * 8);
            bf16x8 k1 = *(const bf16x8*)(karr + (size_t)sA * 128 + l * 8);
            bf16x8 k2 = *(const bf16x8*)(karr + (size_t)sB * 128 + l * 8);
            bf16x8 k3 = *(const bf16x8*)(karr + (size_t)sC * 128 + l * 8);
            float d0 = 0.f, d1 = 0.f, d2 = 0.f, d3 = 0.f;
#pragma unroll
            for (int j = 0; j < 8; j++) {
                d0 += qf[j] * (float)k0[j];
                d1 += qf[j] * (float)k1[j];
                d2 += qf[j] * (float)k2[j];
                d3 += qf[j] * (float)k3[j];
            }
#pragma unroll
            for (int off = 1; off < 16; off <<= 1) {
                d0 += __shfl_xor(d0, off, 64);
                d1 += __shfl_xor(d1, off, 64);
                d2 += __shfl_xor(d2, off, 64);
                d3 += __shfl_xor(d3, off, 64);
            }
            if (l == 0) {
                const float sc = 0.08838834764831845f;
                float a0 = d0 * sc;
                alpha[i] = a0; s1 += a0; s2 += a0 * a0;
                if (i + 4 < end)  { float a = d1 * sc; alpha[i + 4]  = a; s1 += a; s2 += a * a; }
                if (i + 8 < end)  { float a = d2 * sc; alpha[i + 8]  = a; s1 += a; s2 += a * a; }
                if (i + 12 < end) { float a = d3 * sc; alpha[i + 12] = a; s1 += a; s2 += a * a; }
            }
        }
    }
#pragma unroll
    for (int off = 1; off < 64; off <<= 1) {
        s1 += __shfl_xor(s1, off, 64);
        s2 += __shfl_xor(s2, off, 64);
    }
    __shared__ float sh[8];
    int wave = threadIdx.x >> 6;
    if ((threadIdx.x & 63) == 0) { sh[wave] = s1; sh[4 + wave] = s2; }
    __syncthreads();
    if (threadIdx.x == 0) {
        part[2 * blockIdx.x]     = sh[0] + sh[1] + sh[2] + sh[3];
        part[2 * blockIdx.x + 1] = sh[4] + sh[5] + sh[6] + sh[7];
    }
}

__global__ __launch_bounds__(1024) void k_stats(const float* __restrict__ part,
                                                float* __restrict__ S) {
    float s1 = 0.f, s2 = 0.f;
    for (int i = threadIdx.x; i < ALPHA_BLOCKS; i += 1024) {
        s1 += part[2 * i];
        s2 += part[2 * i + 1];
    }
#pragma unroll
    for (int off = 1; off < 64; off <<= 1) {
        s1 += __shfl_xor(s1, off, 64);
        s2 += __shfl_xor(s2, off, 64);
    }
    __shared__ float sh1[16], sh2[16];
    int wave = threadIdx.x >> 6;
    if ((threadIdx.x & 63) == 0) { sh1[wave] = s1; sh2[wave] = s2; }
    __syncthreads();
    if (threadIdx.x == 0) {
        float t1 = 0.f, t2 = 0.f;
#pragma unroll
        for (int w = 0; w < 16; w++) { t1 += sh1[w]; t2 += sh2[w]; }
        float mean = t1 / (float)EEDGES;
        float var = (t2 - (float)EEDGES * mean * mean) / (float)(EEDGES - 1);
        float stdv = sqrtf(fmaxf(var, 1e-20f));
        S[2] = mean;
        S[3] = 3.0f / stdv;
    }
}

// ---------------- output gather (r7 version) ----------------
__global__ __launch_bounds__(256) void k_msg_gather(const int* __restrict__ rowptr,
                                                    const int* __restrict__ srcsorted,
                                                    const __bf16* __restrict__ varr,
                                                    const __bf16* __restrict__ sarr,
                                                    const float* __restrict__ alpha,
                                                    const float* __restrict__ S,
                                                    float* __restrict__ out) {
    int n = (blockIdx.x * 256 + threadIdx.x) >> 6;
    int l = threadIdx.x & 63;
    if (n >= NNODES) return;
    float mean = S[2], scl = S[3];
    bf16x2 sb = *(const bf16x2*)(sarr + (size_t)n * 128 + l * 2);
    float ax = (float)sb[0], ay = (float)sb[1];
    int beg = rowptr[n], end = rowptr[n + 1];
    int deg = end - beg;
    int degc = deg < 64 ? deg : 64;

    int sidx = 0; float gate = 0.f;
    if (l < degc) {
        sidx = srcsorted[beg + l];
        float z = (alpha[beg + l] - mean) * scl;
        gate = 1.0f / (1.0f + __expf(-z));
    }

    for (int e0 = 0; e0 < degc; e0 += 8) {
#pragma unroll
        for (int j = 0; j < 8; j++) {
            int e = e0 + j;
            if (e >= degc) break;                       // wave-uniform
            int s = __builtin_amdgcn_readlane(sidx, e);
            float gv = readlane_f(gate, e);
            bf16x2 v = *(const bf16x2*)(varr + (size_t)s * 128 + l * 2);
            ax += (float)v[0] * gv;
            ay += (float)v[1] * gv;
        }
    }
    for (int i = beg + 64; i < end; i++) {              // rare tail deg>64
        int s = srcsorted[i];
        float z = (alpha[i] - mean) * scl;
        float gv = 1.0f / (1.0f + __expf(-z));
        bf16x2 v = *(const bf16x2*)(varr + (size_t)s * 128 + l * 2);
        ax += (float)v[0] * gv;
        ay += (float)v[1] * gv;
    }
    float2 o; o.x = ax; o.y = ay;
    ((float2*)(out + (size_t)n * DOUT))[l] = o;
}

// ---------------- launch ----------------
extern "C" void kernel_launch(void* const* d_in, const int* in_sizes, int n_in,
                              void* d_out, int out_size, void* d_ws, size_t ws_size,
                              hipStream_t stream) {
    const float* x  = (const float*)d_in[0];
    const int* ei   = (const int*)d_in[1];
    const int* srcI = ei;
    const int* dstI = ei + EEDGES;
    const float* Wg = (const float*)d_in[2];
    const float* bg = (const float*)d_in[3];
    const float* Wq = (const float*)d_in[4];  const float* bq = (const float*)d_in[5];
    const float* Wk = (const float*)d_in[6];  const float* bk = (const float*)d_in[7];
    const float* Wv = (const float*)d_in[8];  const float* bv = (const float*)d_in[9];
    const float* Ws = (const float*)d_in[10]; const float* bs = (const float*)d_in[11];
    float* out = (float*)d_out;

    char* wsb = (char*)d_ws;
    size_t off = 0;
    auto alloc = [&](size_t bytes) -> void* {
        void* p = wsb + off;
        off += (bytes + 255) & ~(size_t)255;
        return p;
    };
    int*    cnt    = (int*)alloc((size_t)NNODES * 4);
    int*    rowptr = (int*)alloc((size_t)(NNODES + 1) * 4);
    int*    epos   = (int*)alloc((size_t)EEDGES * 4);
    int*    srcst  = (int*)alloc((size_t)EEDGES * 4);
    float*  wsort  = (float*)alloc((size_t)EEDGES * 4);
    float*  dinv   = (float*)alloc((size_t)NNODES * 4);
    float*  S      = (float*)alloc(64);
    float*  part   = (float*)alloc((size_t)ALPHA_BLOCKS * 2 * 4);
    __bf16* Wtp    = (__bf16*)alloc((size_t)32 * 8192 * 2);
    __bf16* Wallt  = (__bf16*)alloc((size_t)512 * HMID * 2);
    float*  ball   = (float*)alloc(512 * 4);
    __bf16* h0bf   = (__bf16*)alloc((size_t)NNODES * HMID * 2);
    __bf16* hbf    = (__bf16*)alloc((size_t)NNODES * HMID * 2);
    __bf16* qarr   = (__bf16*)alloc((size_t)NNODES * 128 * 2);
    __bf16* karr   = (__bf16*)alloc((size_t)NNODES * 128 * 2);
    __bf16* varr   = (__bf16*)alloc((size_t)NNODES * 128 * 2);
    __bf16* sarr   = (__bf16*)alloc((size_t)NNODES * 128 * 2);
    float*  alphab = (float*)alloc((size_t)EEDGES * 4);
    if (off > ws_size) return;

    k_prep<<<271, 256, 0, stream>>>(Wg, Wq, Wk, Wv, Ws, bq, bk, bv, bs,
                                    Wtp, Wallt, ball, cnt, S);
    k_count<<<1250, 256, 0, stream>>>(dstI, cnt, epos);
    k_scan<<<1, 1024, 0, stream>>>(cnt, rowptr, dinv);
    k_fill<<<1250, 256, 0, stream>>>(srcI, dstI, rowptr, epos, dinv, srcst, wsort);

    dim3 g1(625, 2);
    k_gemm1<<<g1, 256, 0, stream>>>(x, Wtp, h0bf);

    k_gcn_gather<<<5000, 256, 0, stream>>>(rowptr, srcst, wsort, h0bf, dinv, bg, hbf);

    dim3 g2(313, 4);
    k_gemm2<<<g2, 256, 0, stream>>>(hbf, Wallt, ball, qarr, karr, varr, sarr);

    k_alpha<<<ALPHA_BLOCKS, 256, 0, stream>>>(rowptr, srcst, qarr, karr, alphab, part);
    k_stats<<<1, 1024, 0, stream>>>(part, S);

    k_msg_gather<<<5000, 256, 0, stream>>>(rowptr, srcst, varr, sarr, alphab, S, out);
}